// Round 1
// baseline (772.478 us; speedup 1.0000x reference)
//
#include <hip/hip_runtime.h>

// Wave-autonomous RNN: C = W . x^T orientation (A = weights, B = x/h, C[j][row]).
// One wave owns 16 batch rows through all 256 timesteps and ALL 64 (padded) j's,
// so the h C-frag -> B-frag transpose is wave-private: no s_barrier anywhere,
// just lgkmcnt-ordered LDS. x is loaded global->reg in B-frag layout with a
// 4-step-deep register ring (loop unrolled x4 -> static indexing, no scratch).

#define BATCH   8192
#define TSTEPS  256
#define FIN     64
#define HID     50
#define ROWS    16    // batch rows per wave
#define ST      72    // f16 elems per LDS h-row (64 + 8 pad; b128-aligned: 144 B)
#define PFD     4     // x prefetch depth in steps; t-loop unrolled by PFD

typedef _Float16 f16x8 __attribute__((ext_vector_type(8)));
typedef _Float16 f16x4 __attribute__((ext_vector_type(4)));
typedef float    f32x4 __attribute__((ext_vector_type(4)));

// Drain LDS writes so the following wave-private reads see them (no s_barrier:
// single-wave producer/consumer). "memory" clobber pins LDS op order.
#define LGKM0() asm volatile("s_waitcnt lgkmcnt(0)" ::: "memory")

__device__ __forceinline__ float tanh_fast(float v) {
    // tanh(x) = 1 - 2/(exp2(2*log2e*x)+1); exact at +-inf
    float e = __builtin_amdgcn_exp2f(v * 2.8853900817779268f);
    return 1.0f - 2.0f * __builtin_amdgcn_rcpf(e + 1.0f);
}

__global__ __launch_bounds__(64, 1)
void rnn_fused(const float* __restrict__ x,
               const float* __restrict__ w_ih1, const float* __restrict__ w_hh1,
               const float* __restrict__ b_ih1, const float* __restrict__ b_hh1,
               const float* __restrict__ w_ih2, const float* __restrict__ w_hh2,
               const float* __restrict__ b_ih2, const float* __restrict__ b_hh2,
               const float* __restrict__ fc_w,  const float* __restrict__ fc_b,
               float* __restrict__ out)
{
    __shared__ __align__(16) _Float16 lds_h1[ROWS * ST];
    __shared__ __align__(16) _Float16 lds_h2[ROWS * ST];

    const int lane = threadIdx.x & 63;
    const int c    = lane & 15;   // batch row within tile (B-frag n / C-frag col)
    const int q    = lane >> 4;   // k-group (frags) / C-frag row-group
    const int rowbase = blockIdx.x * ROWS;

    // ---- weights as A-frags: lane holds W[j = jt*16 + c][k = kc*32 + q*8 + i]
    // (identical per-lane layout to the verified B-frag load: A/B frags are
    //  lane-symmetric on gfx950 16x16x32.)
    f16x8 Wih1[4][2], Whh1[4][2], Wih2[4][2], Whh2[4][2];
#pragma unroll
    for (int jt = 0; jt < 4; ++jt) {
        const int j = jt * 16 + c;
#pragma unroll
        for (int kc = 0; kc < 2; ++kc) {
            f16x8 a, b, g, d;
#pragma unroll
            for (int i = 0; i < 8; ++i) {
                const int k = kc * 32 + q * 8 + i;
                a[i] = (_Float16)((j < HID)            ? w_ih1[j * FIN + k] : 0.0f);
                b[i] = (_Float16)((j < HID && k < HID) ? w_hh1[j * HID + k] : 0.0f);
                g[i] = (_Float16)((j < HID && k < HID) ? w_ih2[j * HID + k] : 0.0f);
                d[i] = (_Float16)((j < HID && k < HID) ? w_hh2[j * HID + k] : 0.0f);
            }
            Wih1[jt][kc] = a; Whh1[jt][kc] = b; Wih2[jt][kc] = g; Whh2[jt][kc] = d;
        }
    }

    // ---- per-lane bias / fc vectors over C-frag rows j = jt*16 + q*4 + r
    f32x4 b1v[4], b2v[4], fcv[4];
#pragma unroll
    for (int jt = 0; jt < 4; ++jt) {
#pragma unroll
        for (int r = 0; r < 4; ++r) {
            const int j = jt * 16 + q * 4 + r;
            b1v[jt][r] = (j < HID) ? b_ih1[j] + b_hh1[j] : 0.0f;
            b2v[jt][r] = (j < HID) ? b_ih2[j] + b_hh2[j] : 0.0f;
            fcv[jt][r] = (j < HID) ? fc_w[j] : 0.0f;
        }
    }
    const float fcb = fc_b[0];

    // ---- x prefetch ring: lane reads row (rowbase+c), k = q*8 + kc*32 + {0..7}
    // directly in B-frag layout. 4 x dwordx4 per step, PFD steps deep.
    const float* xrow = x + (size_t)(rowbase + c) * TSTEPS * FIN + q * 8;
    f32x4 xf[PFD][4];
#pragma unroll
    for (int p = 0; p < PFD; ++p) {
        const float* src = xrow + (size_t)p * FIN;
        xf[p][0] = *(const f32x4*)(src);
        xf[p][1] = *(const f32x4*)(src + 4);
        xf[p][2] = *(const f32x4*)(src + 32);
        xf[p][3] = *(const f32x4*)(src + 36);
    }

    f16x8 h1b[2] = {}, h2b[2] = {};   // h(t-1) B-frags, reg-carried; zero at t=0
    f32x4 h2f[4] = {};                // last-step tanh'd h2 (epilogue)

    for (int t0 = 0; t0 < TSTEPS; t0 += PFD) {
#pragma unroll
        for (int u = 0; u < PFD; ++u) {
            const int t = t0 + u;

            // cvt x(t) -> f16 B-frags (vmcnt wait lands here, PFD steps of slack)
            f16x8 xb0, xb1;
#pragma unroll
            for (int i = 0; i < 4; ++i) {
                xb0[i]     = (_Float16)xf[u][0][i];
                xb0[4 + i] = (_Float16)xf[u][1][i];
                xb1[i]     = (_Float16)xf[u][2][i];
                xb1[4 + i] = (_Float16)xf[u][3][i];
            }
            // refill slot u with x(t+PFD)
            {
                const int tn = (t + PFD < TSTEPS) ? t + PFD : TSTEPS - 1;
                const float* src = xrow + (size_t)tn * FIN;
                xf[u][0] = *(const f32x4*)(src);
                xf[u][1] = *(const f32x4*)(src + 4);
                xf[u][2] = *(const f32x4*)(src + 32);
                xf[u][3] = *(const f32x4*)(src + 36);
            }

            // ---- layer 1: C1[j][row] = b1 + Wih1.x^T + Whh1.h1(t-1)^T
            // 4 independent j-tile chains (ILP replaces the lost TLP).
            f32x4 a1[4];
#pragma unroll
            for (int jt = 0; jt < 4; ++jt) {
                f32x4 a = b1v[jt];
                a = __builtin_amdgcn_mfma_f32_16x16x32_f16(Wih1[jt][0], xb0,    a, 0, 0, 0);
                a = __builtin_amdgcn_mfma_f32_16x16x32_f16(Wih1[jt][1], xb1,    a, 0, 0, 0);
                a = __builtin_amdgcn_mfma_f32_16x16x32_f16(Whh1[jt][0], h1b[0], a, 0, 0, 0);
                a = __builtin_amdgcn_mfma_f32_16x16x32_f16(Whh1[jt][1], h1b[1], a, 0, 0, 0);
                a1[jt] = a;
            }
            // tanh + packed b64 publish: h1[row=c][j = jt*16+q*4+r]
            // (jt==3, r>=2 -> j>=50: raw zeros, tanh skipped)
#pragma unroll
            for (int jt = 0; jt < 4; ++jt) {
                f16x4 v;
#pragma unroll
                for (int r = 0; r < 4; ++r) {
                    const float tv = (jt < 3 || r < 2) ? tanh_fast(a1[jt][r]) : a1[jt][r];
                    v[r] = (_Float16)tv;
                }
                *(f16x4*)&lds_h1[c * ST + jt * 16 + q * 4] = v;
            }
            LGKM0();
            // issue h1(t) B-frag reads; the Whh2 MFMAs below cover their latency
            h1b[0] = *(const f16x8*)&lds_h1[c * ST + q * 8];
            h1b[1] = *(const f16x8*)&lds_h1[c * ST + 32 + q * 8];

            // ---- layer 2 part A (h2 recurrent; independent of h1 reads)
            f32x4 a2[4];
#pragma unroll
            for (int jt = 0; jt < 4; ++jt) {
                f32x4 a = b2v[jt];
                a = __builtin_amdgcn_mfma_f32_16x16x32_f16(Whh2[jt][0], h2b[0], a, 0, 0, 0);
                a = __builtin_amdgcn_mfma_f32_16x16x32_f16(Whh2[jt][1], h2b[1], a, 0, 0, 0);
                a2[jt] = a;
            }
            // ---- layer 2 part B (needs h1(t); lgkmcnt wait sunk here by compiler)
#pragma unroll
            for (int jt = 0; jt < 4; ++jt) {
                f32x4 a = a2[jt];
                a = __builtin_amdgcn_mfma_f32_16x16x32_f16(Wih2[jt][0], h1b[0], a, 0, 0, 0);
                a = __builtin_amdgcn_mfma_f32_16x16x32_f16(Wih2[jt][1], h1b[1], a, 0, 0, 0);
                a2[jt] = a;
            }
            // tanh + publish h2; keep f32 values for the epilogue
#pragma unroll
            for (int jt = 0; jt < 4; ++jt) {
                f16x4 v;
#pragma unroll
                for (int r = 0; r < 4; ++r) {
                    const float tv = (jt < 3 || r < 2) ? tanh_fast(a2[jt][r]) : a2[jt][r];
                    h2f[jt][r] = tv;
                    v[r] = (_Float16)tv;
                }
                *(f16x4*)&lds_h2[c * ST + jt * 16 + q * 4] = v;
            }
            LGKM0();
            // h2(t) B-frags for next step; latency hidden under next step's L1
            h2b[0] = *(const f16x8*)&lds_h2[c * ST + q * 8];
            h2b[1] = *(const f16x8*)&lds_h2[c * ST + 32 + q * 8];
        }
    }

    // ---- epilogue: out[row] = sigmoid(sum_j fcw[j]*relu(h2[row][j]) + fcb)
    // lane (q,c) holds j = jt*16+q*4+r for row c; reduce over q via shfl.
    float s = 0.0f;
#pragma unroll
    for (int jt = 0; jt < 4; ++jt)
#pragma unroll
        for (int r = 0; r < 4; ++r) {
            const float h = h2f[jt][r];
            s += fcv[jt][r] * (h > 0.0f ? h : 0.0f);
        }
    s += __shfl_xor(s, 16, 64);
    s += __shfl_xor(s, 32, 64);
    if (lane < 16) {
        const float z = s + fcb;
        const float e = __builtin_amdgcn_exp2f(-z * 1.4426950408889634f);
        out[rowbase + lane] = __builtin_amdgcn_rcpf(1.0f + e);
    }
}

extern "C" void kernel_launch(void* const* d_in, const int* in_sizes, int n_in,
                              void* d_out, int out_size, void* d_ws, size_t ws_size,
                              hipStream_t stream) {
    (void)in_sizes; (void)n_in; (void)out_size; (void)d_ws; (void)ws_size;
    const float* x     = (const float*)d_in[0];
    const float* w_ih1 = (const float*)d_in[1];
    const float* w_hh1 = (const float*)d_in[2];
    const float* b_ih1 = (const float*)d_in[3];
    const float* b_hh1 = (const float*)d_in[4];
    const float* w_ih2 = (const float*)d_in[5];
    const float* w_hh2 = (const float*)d_in[6];
    const float* b_ih2 = (const float*)d_in[7];
    const float* b_hh2 = (const float*)d_in[8];
    const float* fc_w  = (const float*)d_in[9];
    const float* fc_b  = (const float*)d_in[10];
    float* out = (float*)d_out;

    rnn_fused<<<dim3(BATCH / ROWS), dim3(64), 0, stream>>>(
        x, w_ih1, w_hh1, b_ih1, b_hh1, w_ih2, w_hh2, b_ih2, b_hh2, fc_w, fc_b, out);
}

// Round 2
// 759.982 us; speedup vs baseline: 1.0164x; 1.0164x over previous
//
#include <hip/hip_runtime.h>

// 4-stage wave pipeline per 16-row batch tile. Stages (one wave each):
//   C: xp(t) = b1 + Wih1 . x(t)^T           (no recurrence; owns x prefetch)
//   A: h1(t) = tanh(xp(t) + Whh1 . h1(t-1)) (serial; 8 MFMA + 14 tanh)
//   D: p2(t) = b2 + Wih2 . h1(t)
//   B: h2(t) = tanh(p2(t) + Whh2 . h2(t-1)) (serial; + fc epilogue)
// Rings are depth-2, one s_barrier per pipeline tick separates producer and
// consumer (verified: every RAW and WAR pair is split by exactly one barrier).
// xp/p2 hand-off stays in f32 C-frag layout (no transpose). Only A and B do a
// wave-private f16 C->B transpose through LDS (lgkm-ordered, no extra barrier).
// All weights/biases feeding tanh are pre-scaled by 2*log2(e) so
// tanh(v) = 1 - 2/(exp2(v')+1) with no per-element multiply.

#define BATCH   8192
#define TSTEPS  256
#define FIN     64
#define HID     50
#define ROWS    16     // batch rows per tile (MFMA n)
#define ST      72     // f16 elems per LDS h-row (64 + 8 pad)
#define NITER   260    // 256 ticks + 4 fill/drain (multiple of 4 for unroll)
#define SCALE   2.8853900817779268f   // 2*log2(e)

typedef _Float16 f16x8 __attribute__((ext_vector_type(8)));
typedef _Float16 f16x4 __attribute__((ext_vector_type(4)));
typedef float    f32x4 __attribute__((ext_vector_type(4)));

// Raw barrier: drain LDS, leave global loads (x ring) in flight across ticks.
#define BAR()   asm volatile("s_waitcnt lgkmcnt(0)\n\ts_barrier" ::: "memory")
#define LGKM0() asm volatile("s_waitcnt lgkmcnt(0)" ::: "memory")

__device__ __forceinline__ float tanh_pre(float v) {
    // input pre-scaled by 2*log2e; exact at +-inf
    float e = __builtin_amdgcn_exp2f(v);
    return 1.0f - 2.0f * __builtin_amdgcn_rcpf(e + 1.0f);
}

__global__ __launch_bounds__(256, 2)
void rnn_fused(const float* __restrict__ x,
               const float* __restrict__ w_ih1, const float* __restrict__ w_hh1,
               const float* __restrict__ b_ih1, const float* __restrict__ b_hh1,
               const float* __restrict__ w_ih2, const float* __restrict__ w_hh2,
               const float* __restrict__ b_ih2, const float* __restrict__ b_hh2,
               const float* __restrict__ fc_w,  const float* __restrict__ fc_b,
               float* __restrict__ out)
{
    // f32 C-frag rings: [parity][jt][q][c][r] — lane (c,q) writes/reads f32x4
    __shared__ __align__(16) float    lds_xp[2][4][4][16][4];
    __shared__ __align__(16) float    lds_p2[2][4][4][16][4];
    // f16 h1 ring in B-frag-readable layout [parity][row c][j]
    __shared__ __align__(16) _Float16 lds_h1[2][ROWS * ST];
    // wave-private h2 transpose buffer (stage B only)
    __shared__ __align__(16) _Float16 lds_h2[ROWS * ST];

    const int tid  = threadIdx.x;
    const int wid  = tid >> 6;
    const int lane = tid & 63;
    const int c    = lane & 15;   // batch row within tile / C-frag col
    const int q    = lane >> 4;   // k-group / C-frag row-group
    const int rowbase = blockIdx.x * ROWS;

    if (wid == 0) {
        // ================= stage C: xp = b1 + Wih1 . x^T =================
        f16x8 W[4][2];
#pragma unroll
        for (int jt = 0; jt < 4; ++jt) {
            const int j = jt * 16 + c;
#pragma unroll
            for (int kc = 0; kc < 2; ++kc) {
                f16x8 a;
#pragma unroll
                for (int i = 0; i < 8; ++i) {
                    const int k = kc * 32 + q * 8 + i;
                    a[i] = (_Float16)((j < HID) ? w_ih1[j * FIN + k] * SCALE : 0.0f);
                }
                W[jt][kc] = a;
            }
        }
        f32x4 bv[4];
#pragma unroll
        for (int jt = 0; jt < 4; ++jt)
#pragma unroll
            for (int r = 0; r < 4; ++r) {
                const int j = jt * 16 + q * 4 + r;
                bv[jt][r] = (j < HID) ? (b_ih1[j] + b_hh1[j]) * SCALE : 0.0f;
            }

        // x prefetch ring, 4 ticks deep, B-frag layout per lane
        const float* xrow = x + (size_t)(rowbase + c) * TSTEPS * FIN + q * 8;
        f32x4 xf[4][4];
#pragma unroll
        for (int p = 0; p < 4; ++p) {
            const float* src = xrow + (size_t)p * FIN;
            xf[p][0] = *(const f32x4*)(src);
            xf[p][1] = *(const f32x4*)(src + 4);
            xf[p][2] = *(const f32x4*)(src + 32);
            xf[p][3] = *(const f32x4*)(src + 36);
        }

        for (int i0 = 0; i0 < NITER; i0 += 4) {
#pragma unroll
            for (int u = 0; u < 4; ++u) {
                const int i = i0 + u;          // tick; C computes t = i
                if (i < TSTEPS) {
                    f16x8 xb0, xb1;
#pragma unroll
                    for (int e = 0; e < 4; ++e) {
                        xb0[e]     = (_Float16)xf[u][0][e];
                        xb0[4 + e] = (_Float16)xf[u][1][e];
                        xb1[e]     = (_Float16)xf[u][2][e];
                        xb1[4 + e] = (_Float16)xf[u][3][e];
                    }
                    {   // refill slot u with x(t+4)
                        const int tn = (i + 4 < TSTEPS) ? i + 4 : TSTEPS - 1;
                        const float* src = xrow + (size_t)tn * FIN;
                        xf[u][0] = *(const f32x4*)(src);
                        xf[u][1] = *(const f32x4*)(src + 4);
                        xf[u][2] = *(const f32x4*)(src + 32);
                        xf[u][3] = *(const f32x4*)(src + 36);
                    }
#pragma unroll
                    for (int jt = 0; jt < 4; ++jt) {
                        f32x4 a = bv[jt];
                        a = __builtin_amdgcn_mfma_f32_16x16x32_f16(W[jt][0], xb0, a, 0, 0, 0);
                        a = __builtin_amdgcn_mfma_f32_16x16x32_f16(W[jt][1], xb1, a, 0, 0, 0);
                        *(f32x4*)&lds_xp[u & 1][jt][q][c][0] = a;   // parity i&1
                    }
                }
                BAR();
            }
        }
    } else if (wid == 1) {
        // ============ stage A: h1(t) = tanh(xp(t) + Whh1 h1(t-1)) ============
        f16x8 W[4][2];
#pragma unroll
        for (int jt = 0; jt < 4; ++jt) {
            const int j = jt * 16 + c;
#pragma unroll
            for (int kc = 0; kc < 2; ++kc) {
                f16x8 a;
#pragma unroll
                for (int i = 0; i < 8; ++i) {
                    const int k = kc * 32 + q * 8 + i;
                    a[i] = (_Float16)((j < HID && k < HID) ? w_hh1[j * HID + k] * SCALE : 0.0f);
                }
                W[jt][kc] = a;
            }
        }
        f16x8 hb[2] = {};   // h1(t-1) B-frags (zero at t=0)

        for (int i0 = 0; i0 < NITER; i0 += 4) {
#pragma unroll
            for (int u = 0; u < 4; ++u) {
                const int i = i0 + u;          // A computes t = i-1
                if (i >= 1 && i <= TSTEPS) {
                    const int par = (u + 1) & 1;    // (i-1)&1, static
                    f32x4 a[4];
#pragma unroll
                    for (int jt = 0; jt < 4; ++jt)
                        a[jt] = *(const f32x4*)&lds_xp[par][jt][q][c][0];
#pragma unroll
                    for (int jt = 0; jt < 4; ++jt) {
                        a[jt] = __builtin_amdgcn_mfma_f32_16x16x32_f16(W[jt][0], hb[0], a[jt], 0, 0, 0);
                        a[jt] = __builtin_amdgcn_mfma_f32_16x16x32_f16(W[jt][1], hb[1], a[jt], 0, 0, 0);
                    }
#pragma unroll
                    for (int jt = 0; jt < 4; ++jt) {
                        f16x4 v;
#pragma unroll
                        for (int r = 0; r < 4; ++r) {
                            const float tv = (jt < 3 || r < 2) ? tanh_pre(a[jt][r]) : a[jt][r];
                            v[r] = (_Float16)tv;
                        }
                        *(f16x4*)&lds_h1[par][c * ST + jt * 16 + q * 4] = v;
                    }
                    LGKM0();   // own readback for next-step recurrence
                    hb[0] = *(const f16x8*)&lds_h1[par][c * ST + q * 8];
                    hb[1] = *(const f16x8*)&lds_h1[par][c * ST + 32 + q * 8];
                }
                BAR();
            }
        }
    } else if (wid == 2) {
        // ================ stage D: p2(t) = b2 + Wih2 . h1(t) ================
        f16x8 W[4][2];
#pragma unroll
        for (int jt = 0; jt < 4; ++jt) {
            const int j = jt * 16 + c;
#pragma unroll
            for (int kc = 0; kc < 2; ++kc) {
                f16x8 a;
#pragma unroll
                for (int i = 0; i < 8; ++i) {
                    const int k = kc * 32 + q * 8 + i;
                    a[i] = (_Float16)((j < HID && k < HID) ? w_ih2[j * HID + k] * SCALE : 0.0f);
                }
                W[jt][kc] = a;
            }
        }
        f32x4 bv[4];
#pragma unroll
        for (int jt = 0; jt < 4; ++jt)
#pragma unroll
            for (int r = 0; r < 4; ++r) {
                const int j = jt * 16 + q * 4 + r;
                bv[jt][r] = (j < HID) ? (b_ih2[j] + b_hh2[j]) * SCALE : 0.0f;
            }

        for (int i0 = 0; i0 < NITER; i0 += 4) {
#pragma unroll
            for (int u = 0; u < 4; ++u) {
                const int i = i0 + u;          // D computes t = i-2
                if (i >= 2 && i <= TSTEPS + 1) {
                    const int par = u & 1;          // (i-2)&1, static
                    f16x8 hb0 = *(const f16x8*)&lds_h1[par][c * ST + q * 8];
                    f16x8 hb1 = *(const f16x8*)&lds_h1[par][c * ST + 32 + q * 8];
#pragma unroll
                    for (int jt = 0; jt < 4; ++jt) {
                        f32x4 a = bv[jt];
                        a = __builtin_amdgcn_mfma_f32_16x16x32_f16(W[jt][0], hb0, a, 0, 0, 0);
                        a = __builtin_amdgcn_mfma_f32_16x16x32_f16(W[jt][1], hb1, a, 0, 0, 0);
                        *(f32x4*)&lds_p2[par][jt][q][c][0] = a;
                    }
                }
                BAR();
            }
        }
    } else {
        // ============ stage B: h2(t) = tanh(p2(t) + Whh2 h2(t-1)) ============
        f16x8 W[4][2];
#pragma unroll
        for (int jt = 0; jt < 4; ++jt) {
            const int j = jt * 16 + c;
#pragma unroll
            for (int kc = 0; kc < 2; ++kc) {
                f16x8 a;
#pragma unroll
                for (int i = 0; i < 8; ++i) {
                    const int k = kc * 32 + q * 8 + i;
                    a[i] = (_Float16)((j < HID && k < HID) ? w_hh2[j * HID + k] * SCALE : 0.0f);
                }
                W[jt][kc] = a;
            }
        }
        f32x4 fcv[4];
#pragma unroll
        for (int jt = 0; jt < 4; ++jt)
#pragma unroll
            for (int r = 0; r < 4; ++r) {
                const int j = jt * 16 + q * 4 + r;
                fcv[jt][r] = (j < HID) ? fc_w[j] : 0.0f;
            }
        const float fcb = fc_b[0];

        f16x8 hb[2] = {};     // h2(t-1) B-frags
        f32x4 h2f[4] = {};    // last-step tanh'd h2 (epilogue)

        for (int i0 = 0; i0 < NITER; i0 += 4) {
#pragma unroll
            for (int u = 0; u < 4; ++u) {
                const int i = i0 + u;          // B computes t = i-3
                if (i >= 3 && i <= TSTEPS + 2) {
                    const int par = (u + 1) & 1;    // (i-3)&1, static
                    f32x4 a[4];
#pragma unroll
                    for (int jt = 0; jt < 4; ++jt)
                        a[jt] = *(const f32x4*)&lds_p2[par][jt][q][c][0];
#pragma unroll
                    for (int jt = 0; jt < 4; ++jt) {
                        a[jt] = __builtin_amdgcn_mfma_f32_16x16x32_f16(W[jt][0], hb[0], a[jt], 0, 0, 0);
                        a[jt] = __builtin_amdgcn_mfma_f32_16x16x32_f16(W[jt][1], hb[1], a[jt], 0, 0, 0);
                    }
#pragma unroll
                    for (int jt = 0; jt < 4; ++jt) {
                        f16x4 v;
#pragma unroll
                        for (int r = 0; r < 4; ++r) {
                            const float tv = (jt < 3 || r < 2) ? tanh_pre(a[jt][r]) : a[jt][r];
                            h2f[jt][r] = tv;
                            v[r] = (_Float16)tv;
                        }
                        *(f16x4*)&lds_h2[c * ST + jt * 16 + q * 4] = v;
                    }
                    LGKM0();   // wave-private transpose readback
                    hb[0] = *(const f16x8*)&lds_h2[c * ST + q * 8];
                    hb[1] = *(const f16x8*)&lds_h2[c * ST + 32 + q * 8];
                }
                BAR();
            }
        }

        // ---- epilogue: out[row] = sigmoid(sum_j fcw[j]*relu(h2[row][j]) + fcb)
        float s = 0.0f;
#pragma unroll
        for (int jt = 0; jt < 4; ++jt)
#pragma unroll
            for (int r = 0; r < 4; ++r) {
                const float h = h2f[jt][r];
                s += fcv[jt][r] * (h > 0.0f ? h : 0.0f);
            }
        s += __shfl_xor(s, 16, 64);
        s += __shfl_xor(s, 32, 64);
        if (lane < 16) {
            const float z = s + fcb;
            const float e = __builtin_amdgcn_exp2f(-z * 1.4426950408889634f);
            out[rowbase + lane] = __builtin_amdgcn_rcpf(1.0f + e);
        }
    }
}

extern "C" void kernel_launch(void* const* d_in, const int* in_sizes, int n_in,
                              void* d_out, int out_size, void* d_ws, size_t ws_size,
                              hipStream_t stream) {
    (void)in_sizes; (void)n_in; (void)out_size; (void)d_ws; (void)ws_size;
    const float* x     = (const float*)d_in[0];
    const float* w_ih1 = (const float*)d_in[1];
    const float* w_hh1 = (const float*)d_in[2];
    const float* b_ih1 = (const float*)d_in[3];
    const float* b_hh1 = (const float*)d_in[4];
    const float* w_ih2 = (const float*)d_in[5];
    const float* w_hh2 = (const float*)d_in[6];
    const float* b_ih2 = (const float*)d_in[7];
    const float* b_hh2 = (const float*)d_in[8];
    const float* fc_w  = (const float*)d_in[9];
    const float* fc_b  = (const float*)d_in[10];
    float* out = (float*)d_out;

    rnn_fused<<<dim3(BATCH / ROWS), dim3(256), 0, stream>>>(
        x, w_ih1, w_hh1, b_ih1, b_hh1, w_ih2, w_hh2, b_ih2, b_hh2, fc_w, fc_b, out);
}